// Round 9
// baseline (988.013 us; speedup 1.0000x reference)
//
#include <hip/hip_runtime.h>

#define SEQ 512
#define BATCH 256
#define INDIM 256
#define MLP 128
#define M_ROWS (SEQ * BATCH)        // 131072
#define PRE_STRIDE 136              // 128 mlp-pre + 4 gate-pre + 4 pad
#define AUX_OFF ((size_t)M_ROWS * PRE_STRIDE)  // in floats

typedef __attribute__((ext_vector_type(8))) short short8v;   // 8 x bf16 bits
typedef __attribute__((ext_vector_type(4))) float f32x4;

__device__ __forceinline__ ushort bf16_rne(float x) {
  const uint u = __float_as_uint(x);
  return (ushort)((u + 0x7FFFu + ((u >> 16) & 1u)) >> 16);
}

// ---------------------------------------------------------------------------
// Kernel 1: prep — aux sums for rec + b1ext[144] (mlp bias | gate biases | 0)
// aux[0..127]=s1 colsums, aux[128..131]=gate colsums, aux[160..303]=b1ext.
// ---------------------------------------------------------------------------
__global__ __launch_bounds__(256) void prep_kernel(
    const float* __restrict__ W1, const float* __restrict__ b1p,
    const float* __restrict__ Wf, const float* __restrict__ Wi,
    const float* __restrict__ Wg, const float* __restrict__ Wo,
    const float* __restrict__ bf, const float* __restrict__ bi,
    const float* __restrict__ bg, const float* __restrict__ bo,
    float* __restrict__ aux) {
  const int tid = threadIdx.x;
  if (tid < 128) {
    float s = 0.f;
    for (int k = 0; k < 256; ++k) s += W1[(size_t)(256 + k) * 128 + tid];
    aux[tid] = s;
  } else if (tid < 132) {
    const int g = tid - 128;
    const float* w = (g == 0) ? Wf : (g == 1) ? Wi : (g == 2) ? Wg : Wo;
    float s = 0.f;
    for (int k = 0; k < 256; ++k) s += w[256 + k];
    aux[128 + g] = s;
  }
  if (tid < 144) {
    float v;
    if (tid < 128) v = b1p[tid];
    else if (tid < 132) {
      const int g = tid - 128;
      v = (g == 0) ? bf[0] : (g == 1) ? bi[0] : (g == 2) ? bg[0] : bo[0];
    } else v = 0.f;
    aux[160 + tid] = v;
  }
}

// ---------------------------------------------------------------------------
// Kernel 1b: prep2 — W1T_ext bf16 [144 n][264 k-pitch]: cols 0..127 = W1,
// 128..131 = gate weight vectors (first 256 rows), 132..143 = 0.
// ---------------------------------------------------------------------------
__global__ __launch_bounds__(256) void prep2_kernel(
    const float* __restrict__ W1,
    const float* __restrict__ Wf, const float* __restrict__ Wi,
    const float* __restrict__ Wg, const float* __restrict__ Wo,
    ushort* __restrict__ W1T) {
  const int n = blockIdx.x;      // 0..143
  const int k = threadIdx.x;     // 0..255
  float v;
  if (n < 128) v = W1[(size_t)k * 128 + n];
  else if (n < 132) {
    const int g = n - 128;
    const float* w = (g == 0) ? Wf : (g == 1) ? Wi : (g == 2) ? Wg : Wo;
    v = w[k];
  } else v = 0.f;
  W1T[(size_t)n * 264 + k] = bf16_rne(v);
}

// ---------------------------------------------------------------------------
// Kernel 2: bf16 MFMA GEMM. C[M=131072][144] = X[M][256]·W1ext[256][144],
// gate columns fused as B-cols 128..131. Block: BM=64, full N=144, K chunks
// of 32; 4 waves, wave = one 16-row m-tile x 9 n-tiles (9 mfma/chunk).
// A cast fp32->bf16 during staging (X read once, no Xb buffer). LDS rows
// padded to 40 bf16 -> 2-way conflicts only (free per m136).
// ---------------------------------------------------------------------------
__global__ __launch_bounds__(256) void gemm_kernel(
    const float* __restrict__ X, const ushort* __restrict__ W1T,
    const float* __restrict__ b1ext, float* __restrict__ PRE) {
  __shared__ __align__(16) ushort As[64 * 40];
  __shared__ __align__(16) ushort Bs[144 * 40];

  const int tid = threadIdx.x;
  const int lane = tid & 63, wave = tid >> 6;
  const int m = lane & 15, quad = lane >> 4;
  const int arow = tid >> 2, aseg = tid & 3;
  const size_t rowbase = (size_t)blockIdx.x * 64;

  const f32x4 zero = {0.f, 0.f, 0.f, 0.f};
  f32x4 acc[9];
#pragma unroll
  for (int nt = 0; nt < 9; ++nt) acc[nt] = zero;

  for (int kc = 0; kc < 256; kc += 32) {
    __syncthreads();
    // stage A: 64 rows x 32 k, cast to bf16. thread: row=tid>>2, 8-k segment.
    {
      const float* src = &X[(rowbase + arow) * 256 + kc + aseg * 8];
      const float4 v0 = *(const float4*)src;
      const float4 v1 = *(const float4*)(src + 4);
      uint4 w;
      w.x = (uint)bf16_rne(v0.x) | ((uint)bf16_rne(v0.y) << 16);
      w.y = (uint)bf16_rne(v0.z) | ((uint)bf16_rne(v0.w) << 16);
      w.z = (uint)bf16_rne(v1.x) | ((uint)bf16_rne(v1.y) << 16);
      w.w = (uint)bf16_rne(v1.z) | ((uint)bf16_rne(v1.w) << 16);
      *(uint4*)&As[arow * 40 + aseg * 8] = w;
    }
    // stage B: 144 rows x 32 k (already bf16)
    if (tid < 144) {
      const ushort* src = &W1T[(size_t)tid * 264 + kc];
      const uint4 b0 = *(const uint4*)(src + 0);
      const uint4 b1v = *(const uint4*)(src + 8);
      const uint4 b2v = *(const uint4*)(src + 16);
      const uint4 b3v = *(const uint4*)(src + 24);
      *(uint4*)&Bs[tid * 40 + 0] = b0;
      *(uint4*)&Bs[tid * 40 + 8] = b1v;
      *(uint4*)&Bs[tid * 40 + 16] = b2v;
      *(uint4*)&Bs[tid * 40 + 24] = b3v;
    }
    __syncthreads();

    const short8v af = *(const short8v*)&As[(wave * 16 + m) * 40 + quad * 8];
#pragma unroll
    for (int nt = 0; nt < 9; ++nt) {
      const short8v bfr = *(const short8v*)&Bs[(nt * 16 + m) * 40 + quad * 8];
      acc[nt] = __builtin_amdgcn_mfma_f32_16x16x32_bf16(af, bfr, acc[nt], 0, 0, 0);
    }
  }

  // epilogue: C/D layout col=lane&15, row=quad*4+reg [m89]
#pragma unroll
  for (int nt = 0; nt < 9; ++nt) {
    const int col = nt * 16 + m;
    if (col < 132) {
      const float bias = b1ext[col];
      const size_t r0 = rowbase + wave * 16 + quad * 4;
#pragma unroll
      for (int reg = 0; reg < 4; ++reg)
        PRE[(r0 + reg) * PRE_STRIDE + col] = acc[nt][reg] + bias;
    }
  }
}

// ---------------------------------------------------------------------------
// Kernel 3: serial recurrence — TWO chains interleaved in ONE wave (shared
// w2r weights, phases A1 B1 A2 B2 A3 B3 so each chain's latency events are
// covered by the other chain's compute). R8 facts baked in: no lgkm fence
// needed (DS in-order), 16-shfl fused burst, readlane gate collect.
// ---------------------------------------------------------------------------
__device__ __forceinline__ float sigmoid_f(float x) {
  return __fdividef(1.0f, 1.0f + __expf(-x));
}
__device__ __forceinline__ float tanh_f(float x) {
  const float e = __expf(-2.0f * x);
  return __fdividef(1.0f - e, 1.0f + e);
}
__device__ __forceinline__ float readlane_f(float v, int lane) {
  return __int_as_float(__builtin_amdgcn_readlane(__float_as_int(v), lane));
}

__global__ __attribute__((amdgpu_waves_per_eu(1, 1))) __launch_bounds__(64)
void rec_kernel(
    const float* __restrict__ PRE, const float* __restrict__ W2,
    const float* __restrict__ b2, const float* __restrict__ aux,
    float* __restrict__ out) {
  __shared__ __align__(16) float h1sA[128];
  __shared__ __align__(16) float h1sB[128];

  const int l = threadIdx.x;
  const int m = l & 31, half = l >> 5;
  const int g = m >> 3, g8 = g * 8;
  const int bA = blockIdx.x * 2, bB = bA + 1;

  float w2r[64];
#pragma unroll
  for (int u = 0; u < 64; ++u) w2r[u] = W2[(size_t)(half * 64 + u) * 32 + m];
  const float4 b2a = *(const float4*)&b2[g8];
  const float4 b2b = *(const float4*)&b2[g8 + 4];
  const float2 s1 = *(const float2*)&aux[2 * l];
  const float4 sg = *(const float4*)&aux[128];

  float hA = 0.f, cA = 0.f, hB = 0.f, cB = 0.f;

  const float* prA = PRE + (size_t)bA * PRE_STRIDE;
  const float* prB = PRE + (size_t)bB * PRE_STRIDE;
  const size_t ts = (size_t)BATCH * PRE_STRIDE;

  float2 pA0 = *(const float2*)(prA + 0 * ts + 2 * l);
  float4 gA0 = *(const float4*)(prA + 0 * ts + 128);
  float2 pA1 = *(const float2*)(prA + 1 * ts + 2 * l);
  float4 gA1 = *(const float4*)(prA + 1 * ts + 128);
  float2 pB0 = *(const float2*)(prB + 0 * ts + 2 * l);
  float4 gB0 = *(const float4*)(prB + 0 * ts + 128);
  float2 pB1 = *(const float2*)(prB + 1 * ts + 2 * l);
  float4 gB1 = *(const float4*)(prB + 1 * ts + 128);

  const float4* hpA = (const float4*)&h1sA[half * 64];
  const float4* hpB = (const float4*)&h1sB[half * 64];

  for (int t = 0; t < SEQ; ++t) {
    const int tn = (t + 2 < SEQ) ? (t + 2) : (SEQ - 1);

    // ---- A1: publish h1A, classical gates A, rotate A prefetch ----
    const float h10A = fmaxf(fmaf(hA, s1.x, pA0.x), 0.f);
    const float h11A = fmaxf(fmaf(hA, s1.y, pA0.y), 0.f);
    ((float2*)h1sA)[l] = make_float2(h10A, h11A);
    const float cfA = sigmoid_f(fmaf(hA, sg.x, gA0.x));
    const float ciA = sigmoid_f(fmaf(hA, sg.y, gA0.y));
    const float cgA = tanh_f(fmaf(hA, sg.z, gA0.z));
    const float coA = sigmoid_f(fmaf(hA, sg.w, gA0.w));
    pA0 = pA1; gA0 = gA1;
    pA1 = *(const float2*)(prA + (size_t)tn * ts + 2 * l);
    gA1 = *(const float4*)(prA + (size_t)tn * ts + 128);

    // ---- B1: publish h1B, classical gates B, rotate B prefetch ----
    const float h10B = fmaxf(fmaf(hB, s1.x, pB0.x), 0.f);
    const float h11B = fmaxf(fmaf(hB, s1.y, pB0.y), 0.f);
    ((float2*)h1sB)[l] = make_float2(h10B, h11B);
    const float cfB = sigmoid_f(fmaf(hB, sg.x, gB0.x));
    const float ciB = sigmoid_f(fmaf(hB, sg.y, gB0.y));
    const float cgB = tanh_f(fmaf(hB, sg.z, gB0.z));
    const float coB = sigmoid_f(fmaf(hB, sg.w, gB0.w));
    pB0 = pB1; gB0 = gB1;
    pB1 = *(const float2*)(prB + (size_t)tn * ts + 2 * l);
    gB1 = *(const float4*)(prB + (size_t)tn * ts + 128);

    asm volatile("" ::: "memory");  // compiler barrier (DS in-order per wave)

    // ---- A2: matvec A ----
    float qa0 = 0.f, qa1 = 0.f, qa2 = 0.f, qa3 = 0.f;
#pragma unroll
    for (int jj = 0; jj < 16; ++jj) {
      const float4 hv = hpA[jj];
      qa0 = fmaf(hv.x, w2r[4 * jj + 0], qa0);
      qa1 = fmaf(hv.y, w2r[4 * jj + 1], qa1);
      qa2 = fmaf(hv.z, w2r[4 * jj + 2], qa2);
      qa3 = fmaf(hv.w, w2r[4 * jj + 3], qa3);
    }
    const float partA = (qa0 + qa1) + (qa2 + qa3);

    // ---- B2: matvec B ----
    float qb0 = 0.f, qb1 = 0.f, qb2 = 0.f, qb3 = 0.f;
#pragma unroll
    for (int jj = 0; jj < 16; ++jj) {
      const float4 hv = hpB[jj];
      qb0 = fmaf(hv.x, w2r[4 * jj + 0], qb0);
      qb1 = fmaf(hv.y, w2r[4 * jj + 1], qb1);
      qb2 = fmaf(hv.z, w2r[4 * jj + 2], qb2);
      qb3 = fmaf(hv.w, w2r[4 * jj + 3], qb3);
    }
    const float partB = (qb0 + qb1) + (qb2 + qb3);

    // ---- A3: burst + qgate + update + store ----
    {
      const float a0 = __shfl(partA, g8 + 0, 64), b0 = __shfl(partA, 32 + g8 + 0, 64);
      const float a1 = __shfl(partA, g8 + 1, 64), b1 = __shfl(partA, 32 + g8 + 1, 64);
      const float a2 = __shfl(partA, g8 + 2, 64), b2v = __shfl(partA, 32 + g8 + 2, 64);
      const float a3 = __shfl(partA, g8 + 3, 64), b3 = __shfl(partA, 32 + g8 + 3, 64);
      const float a4 = __shfl(partA, g8 + 4, 64), b4 = __shfl(partA, 32 + g8 + 4, 64);
      const float a5 = __shfl(partA, g8 + 5, 64), b5 = __shfl(partA, 32 + g8 + 5, 64);
      const float a6 = __shfl(partA, g8 + 6, 64), b6 = __shfl(partA, 32 + g8 + 6, 64);
      const float a7 = __shfl(partA, g8 + 7, 64), b7 = __shfl(partA, 32 + g8 + 7, 64);
      const float e0 = __cosf(a0 + b0 + b2a.x);
      const float e1 = __cosf(a1 + b1 + b2a.y);
      const float e2 = __cosf(a2 + b2v + b2a.z);
      const float e3 = __cosf(a3 + b3 + b2a.w);
      const float e4 = __cosf(a4 + b4 + b2b.x);
      const float e5 = __cosf(a5 + b5 + b2b.y);
      const float e6 = __cosf(a6 + b6 + b2b.z);
      const float e7 = __cosf(a7 + b7 + b2b.w);
      float p = e0, s = e0;
      p *= e1; s += p; p *= e2; s += p; p *= e3; s += p;
      p *= e4; s += p; p *= e5; s += p; p *= e6; s += p; p *= e7; s += p;
      const float qv = s * 0.125f;
      const float qarg = (g == 2) ? (2.0f * qv) : qv;
      const float qs = sigmoid_f(qarg);
      const float av = (g == 2) ? (2.0f * qs - 1.0f) : qs;
      const float aF = readlane_f(av, 0);
      const float aI = readlane_f(av, 8);
      const float aG = readlane_f(av, 16);
      const float aO = readlane_f(av, 24);
      const float f  = 0.5f * (cfA + aF);
      const float ii = 0.5f * (ciA + aI);
      const float gg = 0.5f * (cgA + aG);
      const float oo = 0.5f * (coA + aO);
      cA = fmaf(f, cA, ii * gg);
      hA = oo * tanh_f(cA);
      float4 hv4o; hv4o.x = hA; hv4o.y = hA; hv4o.z = hA; hv4o.w = hA;
      *(float4*)(out + ((size_t)t * BATCH + bA) * 256 + 4 * l) = hv4o;
    }
    // ---- B3 ----
    {
      const float a0 = __shfl(partB, g8 + 0, 64), b0 = __shfl(partB, 32 + g8 + 0, 64);
      const float a1 = __shfl(partB, g8 + 1, 64), b1 = __shfl(partB, 32 + g8 + 1, 64);
      const float a2 = __shfl(partB, g8 + 2, 64), b2v = __shfl(partB, 32 + g8 + 2, 64);
      const float a3 = __shfl(partB, g8 + 3, 64), b3 = __shfl(partB, 32 + g8 + 3, 64);
      const float a4 = __shfl(partB, g8 + 4, 64), b4 = __shfl(partB, 32 + g8 + 4, 64);
      const float a5 = __shfl(partB, g8 + 5, 64), b5 = __shfl(partB, 32 + g8 + 5, 64);
      const float a6 = __shfl(partB, g8 + 6, 64), b6 = __shfl(partB, 32 + g8 + 6, 64);
      const float a7 = __shfl(partB, g8 + 7, 64), b7 = __shfl(partB, 32 + g8 + 7, 64);
      const float e0 = __cosf(a0 + b0 + b2a.x);
      const float e1 = __cosf(a1 + b1 + b2a.y);
      const float e2 = __cosf(a2 + b2v + b2a.z);
      const float e3 = __cosf(a3 + b3 + b2a.w);
      const float e4 = __cosf(a4 + b4 + b2b.x);
      const float e5 = __cosf(a5 + b5 + b2b.y);
      const float e6 = __cosf(a6 + b6 + b2b.z);
      const float e7 = __cosf(a7 + b7 + b2b.w);
      float p = e0, s = e0;
      p *= e1; s += p; p *= e2; s += p; p *= e3; s += p;
      p *= e4; s += p; p *= e5; s += p; p *= e6; s += p; p *= e7; s += p;
      const float qv = s * 0.125f;
      const float qarg = (g == 2) ? (2.0f * qv) : qv;
      const float qs = sigmoid_f(qarg);
      const float av = (g == 2) ? (2.0f * qs - 1.0f) : qs;
      const float aF = readlane_f(av, 0);
      const float aI = readlane_f(av, 8);
      const float aG = readlane_f(av, 16);
      const float aO = readlane_f(av, 24);
      const float f  = 0.5f * (cfB + aF);
      const float ii = 0.5f * (ciB + aI);
      const float gg = 0.5f * (cgB + aG);
      const float oo = 0.5f * (coB + aO);
      cB = fmaf(f, cB, ii * gg);
      hB = oo * tanh_f(cB);
      float4 hv4o; hv4o.x = hB; hv4o.y = hB; hv4o.z = hB; hv4o.w = hB;
      *(float4*)(out + ((size_t)t * BATCH + bB) * 256 + 4 * l) = hv4o;
    }
  }

  // final (hx, cx) for both chains
  float4 hq, cq;
  hq.x = hA; hq.y = hA; hq.z = hA; hq.w = hA;
  cq.x = cA; cq.y = cA; cq.z = cA; cq.w = cA;
  *(float4*)(out + (size_t)SEQ * BATCH * 256 + (size_t)bA * 256 + 4 * l) = hq;
  *(float4*)(out + (size_t)SEQ * BATCH * 256 + (size_t)BATCH * 256 +
             (size_t)bA * 256 + 4 * l) = cq;
  hq.x = hB; hq.y = hB; hq.z = hB; hq.w = hB;
  cq.x = cB; cq.y = cB; cq.z = cB; cq.w = cB;
  *(float4*)(out + (size_t)SEQ * BATCH * 256 + (size_t)bB * 256 + 4 * l) = hq;
  *(float4*)(out + (size_t)SEQ * BATCH * 256 + (size_t)BATCH * 256 +
             (size_t)bB * 256 + 4 * l) = cq;
}

// ---------------------------------------------------------------------------
extern "C" void kernel_launch(void* const* d_in, const int* in_sizes, int n_in,
                              void* d_out, int out_size, void* d_ws,
                              size_t ws_size, hipStream_t stream) {
  const float* X  = (const float*)d_in[0];
  const float* W1 = (const float*)d_in[1];
  const float* b1 = (const float*)d_in[2];
  const float* W2 = (const float*)d_in[3];
  const float* b2 = (const float*)d_in[4];
  const float* Wf = (const float*)d_in[5];
  const float* bf = (const float*)d_in[6];
  const float* Wi = (const float*)d_in[7];
  const float* bi = (const float*)d_in[8];
  const float* Wg = (const float*)d_in[9];
  const float* bg = (const float*)d_in[10];
  const float* Wo = (const float*)d_in[11];
  const float* bo = (const float*)d_in[12];

  float* ws   = (float*)d_ws;
  float* PRE  = ws;
  float* aux  = ws + AUX_OFF;           // [0..135] rec aux, [160..303] b1ext
  float* b1ext = aux + 160;
  ushort* W1T = (ushort*)(aux + 320);   // 144 x 264 bf16
  float* out  = (float*)d_out;

  prep_kernel<<<1, 256, 0, stream>>>(W1, b1, Wf, Wi, Wg, Wo,
                                     bf, bi, bg, bo, aux);
  prep2_kernel<<<144, 256, 0, stream>>>(W1, Wf, Wi, Wg, Wo, W1T);
  gemm_kernel<<<M_ROWS / 64, 256, 0, stream>>>(X, W1T, b1ext, PRE);
  rec_kernel<<<BATCH / 2, 64, 0, stream>>>(PRE, W2, b2, aux, out);
}